// Round 9
// baseline (125.283 us; speedup 1.0000x reference)
//
#include <hip/hip_runtime.h>
#include <algorithm>
#include <cstdint>

// PRNG: partitionable threefry, 32-bit combine = o0 ^ o1  [VERIFIED R4: absmax=0]
// R8 lesson: global_load_lds staging REGRESSED (+9us) in these latency-bound
// streaming kernels (m97's win is compute-bound-GEMM-specific). Reg-staging here.

constexpr int W_ = 690;
constexpr int NSEG_ = 2 * W_ + 1;   // 1381 segments
constexpr int NCUTS_ = 2 * W_ + 2;  // 1382 cut points
constexpr int TR4_ = 4;             // rows per tile (colsum buffer / gather tile)
constexpr int TFLT_ = TR4_ * W_;    // 2760 floats = 11040 B (16B-aligned tiles)
constexpr int TF4_ = TFLT_ / 4;     // 690 float4 per tile

typedef float v4f_ __attribute__((ext_vector_type(4)));
typedef int v4i_ __attribute__((ext_vector_type(4)));

struct PermArg { unsigned short p[NSEG_]; }; // 2762 B kernarg, values < 1381

// ---------------- host-side threefry2x32 (exact JAX semantics) ----------------
static inline uint32_t rotl32_(uint32_t x, int d) { return (x << d) | (x >> (32 - d)); }

static void tf2x32(uint32_t k0, uint32_t k1, uint32_t x0, uint32_t x1,
                   uint32_t& o0, uint32_t& o1) {
  const uint32_t ks2 = k0 ^ k1 ^ 0x1BD11BDAu;
  x0 += k0; x1 += k1;
  const int RA[4] = {13, 15, 26, 6}, RB[4] = {17, 29, 16, 24};
#define FOUR_(R) for (int i_ = 0; i_ < 4; ++i_) { x0 += x1; x1 = rotl32_(x1, R[i_]); x1 ^= x0; }
  FOUR_(RA) x0 += k1;  x1 += ks2 + 1u;
  FOUR_(RB) x0 += ks2; x1 += k0 + 2u;
  FOUR_(RA) x0 += k0;  x1 += k1 + 3u;
  FOUR_(RB) x0 += k1;  x1 += ks2 + 4u;
  FOUR_(RA) x0 += ks2; x1 += k0 + 5u;
#undef FOUR_
  o0 = x0; o1 = x1;
}

// perm = argsort(uniform(key(42), (1381,))) — pure function of constants.
static void compute_perm(unsigned short* perm) {
  uint32_t uk[NSEG_];
  for (int i = 0; i < NSEG_; ++i) {
    uint32_t o0, o1;
    tf2x32(0u, 42u, 0u, (uint32_t)i, o0, o1); // u64 count i: hi=0 -> x0, lo=i -> x1
    uk[i] = (o0 ^ o1) >> 9; // partitionable bit_width==32: bits1 ^ bits2
  }
  int idx[NSEG_];
  for (int i = 0; i < NSEG_; ++i) idx[i] = i;
  std::stable_sort(idx, idx + NSEG_, [&](int a, int b) { return uk[a] < uk[b]; });
  for (int k = 0; k < NSEG_; ++k) perm[k] = (unsigned short)idx[k];
}

// ---------------- pass 1: double-buffered reg-staged LDS colsum (f64, deterministic) ----------------
__global__ __launch_bounds__(256) void k_colsum(const float* __restrict__ img,
                                                double* __restrict__ partial,
                                                int ntiles, int rows,
                                                unsigned int* __restrict__ counter) {
  __shared__ float buf[2][TFLT_]; // 2 x 11040 B
  const int t = threadIdx.x;
  if (blockIdx.x == 0 && t == 0) *counter = 0; // for fused colreduce_map election
  double a0 = 0.0, a1 = 0.0, a2 = 0.0;

  auto stage = [&](float* bp, int g) {
    const int nr = min(TR4_, rows - g * TR4_);
    if (nr == TR4_) {
      const v4f_* b4 = (const v4f_*)(img + (size_t)g * TFLT_); // 11040B*g: 16B aligned
      v4f_* t4 = (v4f_*)bp;
      for (int i = t; i < TF4_; i += 256) t4[i] = b4[i];
    } else {
      const int nflt = nr * W_;
      const float* b = img + (size_t)g * TFLT_;
      for (int i = t; i < nflt; i += 256) bp[i] = b[i];
    }
  };

  int g = blockIdx.x;
  int phase = 0;
  if (g < ntiles) stage(buf[0], g);
  for (; g < ntiles; g += gridDim.x) {
    __syncthreads(); // buf[phase] staged; prev accumulate of buf[phase^1] done
    const int gn = g + gridDim.x;
    if (gn < ntiles) stage(buf[phase ^ 1], gn); // prefetch next while we accumulate
    const int nr = min(TR4_, rows - g * TR4_);
    const float* bp = buf[phase];
    for (int r = 0; r < nr; ++r) {
      const float* row = bp + r * W_;
      a0 += (double)row[t];
      a1 += (double)row[t + 256];          // t+256 <= 511 < 690 always
      if (t + 512 < W_) a2 += (double)row[t + 512];
    }
    phase ^= 1;
  }
  double* o = partial + (size_t)blockIdx.x * W_;
  o[t] = a0;
  o[t + 256] = a1;
  if (t + 512 < W_) o[t + 512] = a2;
}

// ---------------- hierarchical inclusive scan: 2 barriers, deterministic ----------------
template <int N>
__device__ inline void scan_fast(double* sa, int t, double* wtmp) {
  constexpr int C = (N + 255) / 256;
  double loc[C];
  const int base = t * C;
  double run = 0.0;
#pragma unroll
  for (int j = 0; j < C; ++j) {
    const int i = base + j;
    const double v = (i < N) ? sa[i] : 0.0;
    run += v;
    loc[j] = run;
  }
  const int lane = t & 63, wid = t >> 6;
  double x = run;
#pragma unroll
  for (int off = 1; off < 64; off <<= 1) {
    const double y = __shfl_up(x, off);
    if (lane >= off) x += y;
  }
  if (lane == 63) wtmp[wid] = x;
  __syncthreads(); // all sa reads done; wave totals visible
  double excl = x - run;
  for (int k = 0; k < wid; ++k) excl += wtmp[k];
#pragma unroll
  for (int j = 0; j < C; ++j) {
    const int i = base + j;
    if (i < N) sa[i] = excl + loc[j];
  }
  __syncthreads();
}

// ---------------- the W=690 mapping pipeline (device fn, one block, 256 thr) ----------------
__device__ void map_body(const double* __restrict__ col, int* __restrict__ src,
                         const PermArg& perm, int t) {
  __shared__ double sa[NCUTS_];
  __shared__ double wtmp[4];
  __shared__ float ex[W_ + 1];
  __shared__ unsigned char mm[W_];
  __shared__ int hist[W_ + 1];
  __shared__ int cuts[NCUTS_];
  __shared__ int pl[NSEG_], cum[NSEG_], ssrc[W_];

  // 1) prefix sums of col (f64 scan; cast to f32 like reference cs)
  for (int i = t; i < W_; i += 256) sa[i] = col[i];
  __syncthreads();
  scan_fast<W_>(sa, t, wtmp);
  for (int i = t; i <= W_; i += 256) ex[i] = (i == 0) ? 0.0f : (float)sa[i - 1];
  __syncthreads();

  // 2) windowed mean >= global mean mask
  const float gmean = ex[W_] / 45219840.0f; // n_bc*W = 65536*690
  for (int w = t; w < W_; w += 256) {
    int e = (w + 4 < W_) ? w + 4 : W_;
    float wsum = ex[e] - ex[w];
    float wmean = wsum / ((float)(e - w) * 65536.0f);
    mm[w] = (wmean >= gmean) ? 1 : 0;
  }
  for (int i = t; i <= W_; i += 256) hist[i] = 0;
  __syncthreads();

  // 3) counting-sort histogram of cut values
  for (int w = t; w < W_; w += 256) {
    bool cur = mm[w] != 0;
    bool prv = (w > 0) && (mm[w - 1] != 0);
    bool nxt = (w < W_ - 1) && (mm[w + 1] != 0);
    int sv = (cur && !prv) ? w : W_;
    int lv = (cur && !nxt) ? w : W_;
    atomicAdd(&hist[sv], 1);
    atomicAdd(&hist[lv], 1);
  }
  if (t == 0) { atomicAdd(&hist[0], 1); atomicAdd(&hist[W_], 1); }
  __syncthreads();

  // 4) inclusive scan of histogram
  for (int i = t; i <= W_; i += 256) sa[i] = (double)hist[i];
  __syncthreads();
  scan_fast<W_ + 1>(sa, t, wtmp);
  for (int i = t; i <= W_; i += 256) hist[i] = (int)(sa[i] + 0.5);
  __syncthreads();

  // 5) sorted cuts: cuts[k] = min v with hist_incl[v] > k
  for (int k = t; k < NCUTS_; k += 256) {
    int lo = 0, hi = W_;
    while (lo < hi) { int mid = (lo + hi) >> 1; if (hist[mid] > k) hi = mid; else lo = mid + 1; }
    cuts[k] = lo;
  }
  __syncthreads();

  // 6) permuted lengths + cumulative sum
  for (int k = t; k < NSEG_; k += 256) { int p = perm.p[k]; pl[k] = cuts[p + 1] - cuts[p]; }
  __syncthreads();
  for (int k = t; k < NSEG_; k += 256) sa[k] = (double)pl[k];
  __syncthreads();
  scan_fast<NSEG_>(sa, t, wtmp);
  for (int k = t; k < NSEG_; k += 256) cum[k] = (int)(sa[k] + 0.5);
  __syncthreads();

  // 7) fill src
  for (int k = t; k < NSEG_; k += 256) {
    int L = pl[k];
    if (L > 0) {
      int base = cum[k] - L;
      int s0 = cuts[perm.p[k]];
      for (int j = 0; j < L; ++j) ssrc[base + j] = s0 + j;
    }
  }
  __syncthreads();
  for (int p = t; p < W_; p += 256) src[p] = ssrc[p];
}

// ---------------- pass 2 (fused): colreduce + elected-last-block map ----------------
__global__ __launch_bounds__(256) void k_colreduce_map(const double* __restrict__ partial,
                                                       double* __restrict__ col, int nblk,
                                                       int* __restrict__ src, PermArg perm,
                                                       unsigned int* __restrict__ counter) {
  const int t = threadIdx.x;
  const int lane = t & 63, wid = t >> 6;
  const int w = blockIdx.x * 4 + wid; // 4 columns per block (one per wave)
  if (w < W_) {
    double s = 0.0;
    for (int b = lane; b < nblk; b += 64) s += partial[(size_t)b * W_ + w];
    for (int off = 32; off >= 1; off >>= 1) s += __shfl_down(s, off);
    if (lane == 0) col[w] = s;
  }
  __threadfence(); // release col[] device-wide
  __syncthreads();
  __shared__ int sdone;
  if (t == 0)
    sdone = (atomicAdd(counter, 1u) == (unsigned)(gridDim.x - 1)) ? 1 : 0;
  __syncthreads();
  if (!sdone) return;        // uniform per block
  if (t == 0) *counter = 0;  // reset for next replay (also zeroed by k_colsum)
  __threadfence();           // acquire before reading col[]
  map_body(col, src, perm, t);
}

// ---------------- pass 3: double-buffered reg-staged LDS gather ----------------
// Stage 4 rows coalesced, scatter-read from LDS, nontemporal float4 stores
// (out is never re-read; keep img resident in L3 for gather's re-read).
__global__ __launch_bounds__(256) void k_gather(const float* __restrict__ img,
                                                float* __restrict__ out,
                                                const int* __restrict__ src,
                                                int ntile4, int rows) {
  __shared__ float buf[2][TFLT_];         // 2 x 11040 B
  __shared__ __align__(16) int ss[2 * W_]; // row-resolved source idx (1380)
  const int t = threadIdx.x;
  for (int i = t; i < W_; i += 256) {
    int s = src[i];
    ss[i] = s;
    ss[i + W_] = s + W_;
  }

  auto stage = [&](float* bp, int g) {
    const v4f_* in4 = (const v4f_*)(img + (size_t)g * TFLT_); // 16B aligned
    v4f_* t4 = (v4f_*)bp;
    for (int i = t; i < TF4_; i += 256) t4[i] = in4[i];
  };

  int g = blockIdx.x;
  int phase = 0;
  if (g < ntile4) stage(buf[0], g);
  for (; g < ntile4; g += gridDim.x) {
    __syncthreads(); // buf[phase] staged; prior reads of buf[phase^1] done
    const int gn = g + gridDim.x;
    if (gn < ntile4) stage(buf[phase ^ 1], gn); // prefetch next tile
    const float* bp = buf[phase];
    v4f_* o4 = (v4f_*)(out + (size_t)g * TFLT_);
    for (int q = t; q < TF4_; q += 256) {
      const int f = 4 * q;                       // quads never cross the 1380 boundary
      const int hb = (f >= 2 * W_) ? 2 * W_ : 0; // 2-row half base
      const float* hbuf = bp + hb;
      const v4i_ iv = *(const v4i_*)&ss[f - hb]; // one ds_read_b128
      v4f_ v;
      v[0] = hbuf[iv[0]];
      v[1] = hbuf[iv[1]];
      v[2] = hbuf[iv[2]];
      v[3] = hbuf[iv[3]];
      __builtin_nontemporal_store(v, &o4[q]);
    }
    phase ^= 1;
  }
  // tail rows (rows % 4), scalar — not hit for rows=65536
  const int tail0 = ntile4 * TR4_;
  if (tail0 < rows && blockIdx.x == 0) {
    __syncthreads();
    for (int r = tail0; r < rows; ++r) {
      const float* in = img + (size_t)r * W_;
      float* o = out + (size_t)r * W_;
      for (int p = t; p < W_; p += 256) o[p] = in[ss[p]];
    }
  }
}

extern "C" void kernel_launch(void* const* d_in, const int* in_sizes, int n_in,
                              void* d_out, int out_size, void* d_ws, size_t ws_size,
                              hipStream_t stream) {
  const float* img = (const float*)d_in[0];
  float* out = (float*)d_out;
  const int rows = in_sizes[0] / W_; // 32*2048 = 65536

  // ws layout: col f64[690] @0 | src i32[690] @5632 | counter u32 @8448 | partial @8704
  char* ws = (char*)d_ws;
  double* col = (double*)ws;
  int* src = (int*)(ws + 5632);
  unsigned int* counter = (unsigned int*)(ws + 8448);
  double* partial = (double*)(ws + 8704);
  size_t avail = (ws_size > 8704) ? ws_size - 8704 : 0;
  int nblk = (int)std::min<size_t>(1792, avail / (W_ * sizeof(double)));
  if (nblk < 1) nblk = 1;
  const int ntiles = (rows + TR4_ - 1) / TR4_;
  const int ntile4 = rows / TR4_;

  PermArg pa;
  compute_perm(pa.p); // host, input-independent, deterministic

  k_colsum<<<nblk, 256, 0, stream>>>(img, partial, ntiles, rows, counter);
  k_colreduce_map<<<(W_ + 3) / 4, 256, 0, stream>>>(partial, col, nblk, src, pa, counter);
  k_gather<<<1280, 256, 0, stream>>>(img, out, src, ntile4, rows);
}

// Round 10
// 115.823 us; speedup vs baseline: 1.0817x; 1.0817x over previous
//
#include <hip/hip_runtime.h>
#include <algorithm>
#include <cstdint>

// PRNG: partitionable threefry, 32-bit combine = o0 ^ o1  [VERIFIED R4: absmax=0]
// R8 lesson: global_load_lds staging was NEUTRAL here (R8 vs R9).
// R9 lesson: colreduce+map fusion REGRESSED +9us — per-block __threadfence()
// (device-scope release across non-coherent XCD L2s) costs more than the saved
// launch gap. Separate dispatches rely on stream ordering instead.

constexpr int W_ = 690;
constexpr int NSEG_ = 2 * W_ + 1;   // 1381 segments
constexpr int NCUTS_ = 2 * W_ + 2;  // 1382 cut points
constexpr int TR4_ = 4;             // rows per tile (colsum buffer / gather tile)
constexpr int TFLT_ = TR4_ * W_;    // 2760 floats = 11040 B (16B-aligned tiles)
constexpr int TF4_ = TFLT_ / 4;     // 690 float4 per tile

typedef float v4f_ __attribute__((ext_vector_type(4)));
typedef int v4i_ __attribute__((ext_vector_type(4)));

struct PermArg { unsigned short p[NSEG_]; }; // 2762 B kernarg, values < 1381

// ---------------- host-side threefry2x32 (exact JAX semantics) ----------------
static inline uint32_t rotl32_(uint32_t x, int d) { return (x << d) | (x >> (32 - d)); }

static void tf2x32(uint32_t k0, uint32_t k1, uint32_t x0, uint32_t x1,
                   uint32_t& o0, uint32_t& o1) {
  const uint32_t ks2 = k0 ^ k1 ^ 0x1BD11BDAu;
  x0 += k0; x1 += k1;
  const int RA[4] = {13, 15, 26, 6}, RB[4] = {17, 29, 16, 24};
#define FOUR_(R) for (int i_ = 0; i_ < 4; ++i_) { x0 += x1; x1 = rotl32_(x1, R[i_]); x1 ^= x0; }
  FOUR_(RA) x0 += k1;  x1 += ks2 + 1u;
  FOUR_(RB) x0 += ks2; x1 += k0 + 2u;
  FOUR_(RA) x0 += k0;  x1 += k1 + 3u;
  FOUR_(RB) x0 += k1;  x1 += ks2 + 4u;
  FOUR_(RA) x0 += ks2; x1 += k0 + 5u;
#undef FOUR_
  o0 = x0; o1 = x1;
}

// perm = argsort(uniform(key(42), (1381,))) — pure function of constants.
static void compute_perm(unsigned short* perm) {
  uint32_t uk[NSEG_];
  for (int i = 0; i < NSEG_; ++i) {
    uint32_t o0, o1;
    tf2x32(0u, 42u, 0u, (uint32_t)i, o0, o1); // u64 count i: hi=0 -> x0, lo=i -> x1
    uk[i] = (o0 ^ o1) >> 9; // partitionable bit_width==32: bits1 ^ bits2
  }
  int idx[NSEG_];
  for (int i = 0; i < NSEG_; ++i) idx[i] = i;
  std::stable_sort(idx, idx + NSEG_, [&](int a, int b) { return uk[a] < uk[b]; });
  for (int k = 0; k < NSEG_; ++k) perm[k] = (unsigned short)idx[k];
}

// ---------------- pass 1: double-buffered reg-staged LDS colsum (f64, deterministic) ----------------
__global__ __launch_bounds__(256) void k_colsum(const float* __restrict__ img,
                                                double* __restrict__ partial,
                                                int ntiles, int rows) {
  __shared__ float buf[2][TFLT_]; // 2 x 11040 B
  const int t = threadIdx.x;
  double a0 = 0.0, a1 = 0.0, a2 = 0.0;

  auto stage = [&](float* bp, int g) {
    const int nr = min(TR4_, rows - g * TR4_);
    if (nr == TR4_) {
      const v4f_* b4 = (const v4f_*)(img + (size_t)g * TFLT_); // 11040B*g: 16B aligned
      v4f_* t4 = (v4f_*)bp;
      for (int i = t; i < TF4_; i += 256) t4[i] = b4[i];
    } else {
      const int nflt = nr * W_;
      const float* b = img + (size_t)g * TFLT_;
      for (int i = t; i < nflt; i += 256) bp[i] = b[i];
    }
  };

  int g = blockIdx.x;
  int phase = 0;
  if (g < ntiles) stage(buf[0], g);
  for (; g < ntiles; g += gridDim.x) {
    __syncthreads(); // buf[phase] staged; prev accumulate of buf[phase^1] done
    const int gn = g + gridDim.x;
    if (gn < ntiles) stage(buf[phase ^ 1], gn); // prefetch next while we accumulate
    const int nr = min(TR4_, rows - g * TR4_);
    const float* bp = buf[phase];
    for (int r = 0; r < nr; ++r) {
      const float* row = bp + r * W_;
      a0 += (double)row[t];
      a1 += (double)row[t + 256];          // t+256 <= 511 < 690 always
      if (t + 512 < W_) a2 += (double)row[t + 512];
    }
    phase ^= 1;
  }
  double* o = partial + (size_t)blockIdx.x * W_;
  o[t] = a0;
  o[t + 256] = a1;
  if (t + 512 < W_) o[t + 512] = a2;
}

// ---------------- pass 1b: fixed-order tree reduction of partials ----------------
__global__ __launch_bounds__(64) void k_colreduce(const double* __restrict__ partial,
                                                  double* __restrict__ col, int nblk) {
  const int w = blockIdx.x;       // 690 blocks
  const int lane = threadIdx.x;   // one wave
  double s = 0.0;
  for (int b = lane; b < nblk; b += 64) s += partial[(size_t)b * W_ + w];
  for (int off = 32; off >= 1; off >>= 1) s += __shfl_down(s, off);
  if (lane == 0) col[w] = s;
}

// ---------------- hierarchical inclusive scan: 2 barriers, deterministic ----------------
template <int N>
__device__ inline void scan_fast(double* sa, int t, double* wtmp) {
  constexpr int C = (N + 255) / 256;
  double loc[C];
  const int base = t * C;
  double run = 0.0;
#pragma unroll
  for (int j = 0; j < C; ++j) {
    const int i = base + j;
    const double v = (i < N) ? sa[i] : 0.0;
    run += v;
    loc[j] = run;
  }
  const int lane = t & 63, wid = t >> 6;
  double x = run;
#pragma unroll
  for (int off = 1; off < 64; off <<= 1) {
    const double y = __shfl_up(x, off);
    if (lane >= off) x += y;
  }
  if (lane == 63) wtmp[wid] = x;
  __syncthreads(); // all sa reads done; wave totals visible
  double excl = x - run;
  for (int k = 0; k < wid; ++k) excl += wtmp[k];
#pragma unroll
  for (int j = 0; j < C; ++j) {
    const int i = base + j;
    if (i < N) sa[i] = excl + loc[j];
  }
  __syncthreads();
}

// ---------------- pass 2: the whole W=690 mapping pipeline, one block ----------------
__global__ __launch_bounds__(256) void k_map(const double* __restrict__ col,
                                             int* __restrict__ src, PermArg perm) {
  __shared__ double sa[NCUTS_];
  __shared__ double wtmp[4];
  __shared__ float ex[W_ + 1];
  __shared__ unsigned char mm[W_];
  __shared__ int hist[W_ + 1];
  __shared__ int cuts[NCUTS_];
  __shared__ int pl[NSEG_], cum[NSEG_], ssrc[W_];
  const int t = threadIdx.x;

  // 1) prefix sums of col (f64 scan; cast to f32 like reference cs)
  for (int i = t; i < W_; i += 256) sa[i] = col[i];
  __syncthreads();
  scan_fast<W_>(sa, t, wtmp);
  for (int i = t; i <= W_; i += 256) ex[i] = (i == 0) ? 0.0f : (float)sa[i - 1];
  __syncthreads();

  // 2) windowed mean >= global mean mask
  const float gmean = ex[W_] / 45219840.0f; // n_bc*W = 65536*690
  for (int w = t; w < W_; w += 256) {
    int e = (w + 4 < W_) ? w + 4 : W_;
    float wsum = ex[e] - ex[w];
    float wmean = wsum / ((float)(e - w) * 65536.0f);
    mm[w] = (wmean >= gmean) ? 1 : 0;
  }
  for (int i = t; i <= W_; i += 256) hist[i] = 0;
  __syncthreads();

  // 3) counting-sort histogram of cut values
  for (int w = t; w < W_; w += 256) {
    bool cur = mm[w] != 0;
    bool prv = (w > 0) && (mm[w - 1] != 0);
    bool nxt = (w < W_ - 1) && (mm[w + 1] != 0);
    int sv = (cur && !prv) ? w : W_;
    int lv = (cur && !nxt) ? w : W_;
    atomicAdd(&hist[sv], 1);
    atomicAdd(&hist[lv], 1);
  }
  if (t == 0) { atomicAdd(&hist[0], 1); atomicAdd(&hist[W_], 1); }
  __syncthreads();

  // 4) inclusive scan of histogram
  for (int i = t; i <= W_; i += 256) sa[i] = (double)hist[i];
  __syncthreads();
  scan_fast<W_ + 1>(sa, t, wtmp);
  for (int i = t; i <= W_; i += 256) hist[i] = (int)(sa[i] + 0.5);
  __syncthreads();

  // 5) sorted cuts: cuts[k] = min v with hist_incl[v] > k
  for (int k = t; k < NCUTS_; k += 256) {
    int lo = 0, hi = W_;
    while (lo < hi) { int mid = (lo + hi) >> 1; if (hist[mid] > k) hi = mid; else lo = mid + 1; }
    cuts[k] = lo;
  }
  __syncthreads();

  // 6) permuted lengths + cumulative sum
  for (int k = t; k < NSEG_; k += 256) { int p = perm.p[k]; pl[k] = cuts[p + 1] - cuts[p]; }
  __syncthreads();
  for (int k = t; k < NSEG_; k += 256) sa[k] = (double)pl[k];
  __syncthreads();
  scan_fast<NSEG_>(sa, t, wtmp);
  for (int k = t; k < NSEG_; k += 256) cum[k] = (int)(sa[k] + 0.5);
  __syncthreads();

  // 7) fill src
  for (int k = t; k < NSEG_; k += 256) {
    int L = pl[k];
    if (L > 0) {
      int base = cum[k] - L;
      int s0 = cuts[perm.p[k]];
      for (int j = 0; j < L; ++j) ssrc[base + j] = s0 + j;
    }
  }
  __syncthreads();
  for (int p = t; p < W_; p += 256) src[p] = ssrc[p];
}

// ---------------- pass 3: double-buffered reg-staged LDS gather ----------------
// Stage 4 rows coalesced, scatter-read from LDS, nontemporal float4 stores
// (out is never re-read; keep img resident in L3 for gather's re-read).
__global__ __launch_bounds__(256) void k_gather(const float* __restrict__ img,
                                                float* __restrict__ out,
                                                const int* __restrict__ src,
                                                int ntile4, int rows) {
  __shared__ float buf[2][TFLT_];          // 2 x 11040 B
  __shared__ __align__(16) int ss[2 * W_]; // row-resolved source idx (1380)
  const int t = threadIdx.x;
  for (int i = t; i < W_; i += 256) {
    int s = src[i];
    ss[i] = s;
    ss[i + W_] = s + W_;
  }

  auto stage = [&](float* bp, int g) {
    const v4f_* in4 = (const v4f_*)(img + (size_t)g * TFLT_); // 16B aligned
    v4f_* t4 = (v4f_*)bp;
    for (int i = t; i < TF4_; i += 256) t4[i] = in4[i];
  };

  int g = blockIdx.x;
  int phase = 0;
  if (g < ntile4) stage(buf[0], g);
  for (; g < ntile4; g += gridDim.x) {
    __syncthreads(); // buf[phase] staged; prior reads of buf[phase^1] done
    const int gn = g + gridDim.x;
    if (gn < ntile4) stage(buf[phase ^ 1], gn); // prefetch next tile
    const float* bp = buf[phase];
    v4f_* o4 = (v4f_*)(out + (size_t)g * TFLT_);
    for (int q = t; q < TF4_; q += 256) {
      const int f = 4 * q;                       // quads never cross the 1380 boundary
      const int hb = (f >= 2 * W_) ? 2 * W_ : 0; // 2-row half base
      const float* hbuf = bp + hb;
      const v4i_ iv = *(const v4i_*)&ss[f - hb]; // one ds_read_b128
      v4f_ v;
      v[0] = hbuf[iv[0]];
      v[1] = hbuf[iv[1]];
      v[2] = hbuf[iv[2]];
      v[3] = hbuf[iv[3]];
      __builtin_nontemporal_store(v, &o4[q]);
    }
    phase ^= 1;
  }
  // tail rows (rows % 4), scalar — not hit for rows=65536
  const int tail0 = ntile4 * TR4_;
  if (tail0 < rows && blockIdx.x == 0) {
    __syncthreads();
    for (int r = tail0; r < rows; ++r) {
      const float* in = img + (size_t)r * W_;
      float* o = out + (size_t)r * W_;
      for (int p = t; p < W_; p += 256) o[p] = in[ss[p]];
    }
  }
}

extern "C" void kernel_launch(void* const* d_in, const int* in_sizes, int n_in,
                              void* d_out, int out_size, void* d_ws, size_t ws_size,
                              hipStream_t stream) {
  const float* img = (const float*)d_in[0];
  float* out = (float*)d_out;
  const int rows = in_sizes[0] / W_; // 32*2048 = 65536

  // ws layout: col f64[690] @0 | src i32[690] @5632 | partial @8704
  char* ws = (char*)d_ws;
  double* col = (double*)ws;
  int* src = (int*)(ws + 5632);
  double* partial = (double*)(ws + 8704);
  size_t avail = (ws_size > 8704) ? ws_size - 8704 : 0;
  int nblk = (int)std::min<size_t>(1792, avail / (W_ * sizeof(double)));
  if (nblk < 1) nblk = 1;
  const int ntiles = (rows + TR4_ - 1) / TR4_;
  const int ntile4 = rows / TR4_;

  PermArg pa;
  compute_perm(pa.p); // host, input-independent, deterministic

  k_colsum<<<nblk, 256, 0, stream>>>(img, partial, ntiles, rows);
  k_colreduce<<<W_, 64, 0, stream>>>(partial, col, nblk);
  k_map<<<1, 256, 0, stream>>>(col, src, pa);
  k_gather<<<1280, 256, 0, stream>>>(img, out, src, ntile4, rows);
}